// Round 10
// baseline (170.732 us; speedup 1.0000x reference)
//
#include <hip/hip_runtime.h>
#include <hip/hip_bf16.h>
#include <math.h>

#define B_   128
#define Qn   30
#define Dn   200
#define En   300

typedef __attribute__((ext_vector_type(8))) short short8;
typedef __attribute__((ext_vector_type(4))) float floatx4;
typedef unsigned int u32;
typedef unsigned short u16;

static __device__ __forceinline__ u16 f2b(float x) {   // fp32 -> bf16 RNE
    union { float f; u32 u; } v; v.f = x;
    u32 r = v.u + 0x7FFFu + ((v.u >> 16) & 1u);
    return (u16)(r >> 16);
}
static __device__ __forceinline__ float bits2f(u32 u) {
    union { u32 u2; float f; } v; v.u2 = u; return v.f;
}

// asm load: issues at program point; compiler cannot sink it (R7 lesson:
// source-level hoisting is always re-sunk). Completion is OUR job via
// counted s_waitcnt vmcnt(N) + sched_barrier(0) (rule #18).
static __device__ __forceinline__ short8 gload16(const u16* p) {
    short8 r;
    asm volatile("global_load_dwordx4 %0, %1, off" : "=&v"(r) : "v"(p));
    return r;
}

// ---------------------------------------------------------------------------
// prep: weight permute ONLY. ks-major: one K-slice = contiguous 48 KB:
//   Wt3[ks 10][ g1 j0 (8 chunks) | g2 j0,j1 (16) | g3 j0..j2 (24) ] x 1KB
// ---------------------------------------------------------------------------
__global__ void prep_kernel(
    const float* __restrict__ w1, const float* __restrict__ w2, const float* __restrict__ w3,
    u16* __restrict__ Wt3)
{
    int p = (blockIdx.x*128 + blockIdx.y)*256 + threadIdx.x;
    if (p >= 245760) return;
    int ks = p / 24576;
    int r  = p - ks*24576;
    int g, rr;
    if (r < 4096)        { g = 0; rr = r;         }
    else if (r < 12288)  { g = 1; rr = r - 4096;  }
    else                 { g = 2; rr = r - 12288; }
    int j  = rr >> 12;
    int r2 = rr & 4095;
    int nt  = r2 >> 9;
    int q4  = (r2 >> 7) & 3;
    int c16 = (r2 >> 3) & 15;
    int k8  = r2 & 7;
    int ch = nt*16 + c16;
    int e  = ks*32 + q4*8 + k8;
    float v = 0.f;
    if (e < En) {
        if (g == 0)      v = w1[ch*En + e];
        else if (g == 1) v = w2[(ch*En + e)*2 + j];
        else             v = w3[(ch*En + e)*3 + j];
    }
    Wt3[p] = f2b(v);
}

// ---------------------------------------------------------------------------
// Fused conv, R10: R4 geometry + counted-vmcnt software pipeline on the B
// weight loads (asm volatile global_load_dwordx4, double-buffered register
// sets wa/wb, s_waitcnt vmcnt(12) per stage -> ONE batched L2 stall per
// K-slice instead of six compiler-sunk serial stalls). MFMA order per
// output identical to R4 => bit-identical results.
// ---------------------------------------------------------------------------
#define MFMA __builtin_amdgcn_mfma_f32_16x16x32_bf16

#define LOADB(P, KS) { \
    const u16* _b = Wt3 + (KS)*24576 + nh*1024 + lane*8; \
    P##0  = gload16(_b);          P##1  = gload16(_b + 512); \
    P##2  = gload16(_b + 4096);   P##3  = gload16(_b + 4608); \
    P##4  = gload16(_b + 8192);   P##5  = gload16(_b + 8704); \
    P##6  = gload16(_b + 12288);  P##7  = gload16(_b + 12800); \
    P##8  = gload16(_b + 16384);  P##9  = gload16(_b + 16896); \
    P##10 = gload16(_b + 20480);  P##11 = gload16(_b + 20992); }

#define AFLOAD(KS) \
    short8 af00 = *(const short8*)(As + (mh*32 +  0 + l15 + 0)*656 + (KS)*64 + qd4*16); \
    short8 af01 = *(const short8*)(As + (mh*32 +  0 + l15 + 1)*656 + (KS)*64 + qd4*16); \
    short8 af02 = *(const short8*)(As + (mh*32 +  0 + l15 + 2)*656 + (KS)*64 + qd4*16); \
    short8 af10 = *(const short8*)(As + (mh*32 + 16 + l15 + 0)*656 + (KS)*64 + qd4*16); \
    short8 af11 = *(const short8*)(As + (mh*32 + 16 + l15 + 1)*656 + (KS)*64 + qd4*16); \
    short8 af12 = *(const short8*)(As + (mh*32 + 16 + l15 + 2)*656 + (KS)*64 + qd4*16);

#define VMWAIT12 { asm volatile("s_waitcnt vmcnt(12)" ::: "memory"); __builtin_amdgcn_sched_barrier(0); }
#define VMWAIT0  { asm volatile("s_waitcnt vmcnt(0)"  ::: "memory"); __builtin_amdgcn_sched_barrier(0); }

#define MFMAS(P) \
    acc[0][0][0] = MFMA(af00, P##0,  acc[0][0][0], 0,0,0); \
    acc[0][0][1] = MFMA(af00, P##1,  acc[0][0][1], 0,0,0); \
    acc[0][1][0] = MFMA(af10, P##0,  acc[0][1][0], 0,0,0); \
    acc[0][1][1] = MFMA(af10, P##1,  acc[0][1][1], 0,0,0); \
    acc[1][0][0] = MFMA(af00, P##2,  acc[1][0][0], 0,0,0); \
    acc[1][0][1] = MFMA(af00, P##3,  acc[1][0][1], 0,0,0); \
    acc[1][1][0] = MFMA(af10, P##2,  acc[1][1][0], 0,0,0); \
    acc[1][1][1] = MFMA(af10, P##3,  acc[1][1][1], 0,0,0); \
    acc[1][0][0] = MFMA(af01, P##4,  acc[1][0][0], 0,0,0); \
    acc[1][0][1] = MFMA(af01, P##5,  acc[1][0][1], 0,0,0); \
    acc[1][1][0] = MFMA(af11, P##4,  acc[1][1][0], 0,0,0); \
    acc[1][1][1] = MFMA(af11, P##5,  acc[1][1][1], 0,0,0); \
    acc[2][0][0] = MFMA(af00, P##6,  acc[2][0][0], 0,0,0); \
    acc[2][0][1] = MFMA(af00, P##7,  acc[2][0][1], 0,0,0); \
    acc[2][1][0] = MFMA(af10, P##6,  acc[2][1][0], 0,0,0); \
    acc[2][1][1] = MFMA(af10, P##7,  acc[2][1][1], 0,0,0); \
    acc[2][0][0] = MFMA(af01, P##8,  acc[2][0][0], 0,0,0); \
    acc[2][0][1] = MFMA(af01, P##9,  acc[2][0][1], 0,0,0); \
    acc[2][1][0] = MFMA(af11, P##8,  acc[2][1][0], 0,0,0); \
    acc[2][1][1] = MFMA(af11, P##9,  acc[2][1][1], 0,0,0); \
    acc[2][0][0] = MFMA(af02, P##10, acc[2][0][0], 0,0,0); \
    acc[2][0][1] = MFMA(af02, P##11, acc[2][0][1], 0,0,0); \
    acc[2][1][0] = MFMA(af12, P##10, acc[2][1][0], 0,0,0); \
    acc[2][1][1] = MFMA(af12, P##11, acc[2][1][1], 0,0,0);

__global__ __launch_bounds__(512, 2) void conv_kernel(
    const int* __restrict__ qtok, const int* __restrict__ dtok,
    const float* __restrict__ emb,
    const u16* __restrict__ Wt3,
    const float* __restrict__ b1, const float* __restrict__ b2, const float* __restrict__ b3,
    u16* __restrict__ qg, u16* __restrict__ dg,
    float* __restrict__ invnq, float* __restrict__ invnd)
{
    __shared__ __align__(16) char smem[43560];   // As [66][656] + toks[66]
    char* As  = smem;
    int*  toks = (int*)(smem + 43296);

    const int tile = blockIdx.x;
    const int tid = threadIdx.x;
    const int wv = tid >> 6, lane = tid & 63;
    const int l15 = lane & 15, qd4 = lane >> 4;
    const int mh = wv >> 2, nh = wv & 3;
    const int gR0 = tile*64;

    if (tid < 66) {
        int gr = gR0 + tid;
        int t = -1;
        if (gr < 32768) {
            int b = gr >> 8, pos = gr & 255;
            if (pos < Dn) t = dtok[b*Dn + pos];
            else if (pos >= 208 && pos < 238) t = qtok[b*Qn + (pos - 208)];
        }
        toks[tid] = t;
    }
    __syncthreads();

    // stage A K-lo: 66 rows x col4 0..39 (K elems 0..159) — all ks 0..4 reads
    #pragma unroll
    for (int i = 0; i < 6; ++i) {
        int idx = tid + i*512;
        if (idx < 2640) {
            int r = idx / 40, c4 = idx - r*40;
            int t = toks[r];
            u16 o0=0,o1=0,o2=0,o3=0;
            if (t >= 0) {
                float4 v = *(const float4*)(emb + t*En + c4*4);
                o0=f2b(v.x); o1=f2b(v.y); o2=f2b(v.z); o3=f2b(v.w);
            }
            u16* pdst = (u16*)(As + r*656 + c4*8);
            pdst[0]=o0; pdst[1]=o1; pdst[2]=o2; pdst[3]=o3;
        }
    }

    float bias[3][2];
    #pragma unroll
    for (int nt = 0; nt < 2; ++nt) {
        int ch = nh*32 + nt*16 + l15;
        bias[0][nt] = b1[ch];
        bias[1][nt] = b2[ch];
        bias[2][nt] = b3[ch];
    }

    floatx4 acc[3][2][2];
    #pragma unroll
    for (int g = 0; g < 3; ++g)
        #pragma unroll
        for (int mt = 0; mt < 2; ++mt)
            #pragma unroll
            for (int nt = 0; nt < 2; ++nt)
                acc[g][mt][nt] = (floatx4){0.f,0.f,0.f,0.f};

    __syncthreads();                        // A K-lo ready (drains all vmem)

    // K-hi loads (cols 160..319) issued into registers; fly under ks 0..4.
    float4 hf[6];
    #pragma unroll
    for (int i = 0; i < 6; ++i) {
        int idx = tid + i*512;
        const float* p = emb;               // safe dummy
        if (idx < 2640) {
            int r = idx / 40, c = idx - r*40;
            int t = toks[r];
            if (t >= 0 && c < 35) p = emb + t*En + (40 + c)*4;
        }
        hf[i] = *(const float4*)p;
    }

    short8 wa0,wa1,wa2,wa3,wa4,wa5,wa6,wa7,wa8,wa9,wa10,wa11;
    short8 wb0,wb1,wb2,wb3,wb4,wb5,wb6,wb7,wb8,wb9,wb10,wb11;

    LOADB(wa, 0)
    { LOADB(wb, 1) AFLOAD(0) VMWAIT12 MFMAS(wa) }
    { LOADB(wa, 2) AFLOAD(1) VMWAIT12 MFMAS(wb) }
    { LOADB(wb, 3) AFLOAD(2) VMWAIT12 MFMAS(wa) }
    { LOADB(wa, 4) AFLOAD(3) VMWAIT12 MFMAS(wb) }
    { LOADB(wb, 5) AFLOAD(4) VMWAIT12 MFMAS(wa) }

    // write K-hi into As (region untouched by ks 0..4 reads), one barrier.
    // The barrier's vmcnt(0) drain also lands wb(ks5) — harmless.
    #pragma unroll
    for (int i = 0; i < 6; ++i) {
        int idx = tid + i*512;
        if (idx < 2640) {
            int r = idx / 40, c = idx - r*40;
            int t = toks[r];
            bool ok = (t >= 0) && (c < 35);
            u16 o0=0,o1=0,o2=0,o3=0;
            if (ok) { o0=f2b(hf[i].x); o1=f2b(hf[i].y); o2=f2b(hf[i].z); o3=f2b(hf[i].w); }
            u16* pdst = (u16*)(As + r*656 + (40 + c)*8);
            pdst[0]=o0; pdst[1]=o1; pdst[2]=o2; pdst[3]=o3;
        }
    }
    __syncthreads();                        // K-hi ready

    { LOADB(wa, 6) AFLOAD(5) VMWAIT12 MFMAS(wb) }
    { LOADB(wb, 7) AFLOAD(6) VMWAIT12 MFMAS(wa) }
    { LOADB(wa, 8) AFLOAD(7) VMWAIT12 MFMAS(wb) }
    { LOADB(wb, 9) AFLOAD(8) VMWAIT12 MFMAS(wa) }
    {              AFLOAD(9) VMWAIT0  MFMAS(wb) }

    // epilogue: per-gram Gs overlay on As; fully unrolled over g (rule #20);
    // norms across all 512 threads (8 lanes/row + shfl_xor).
    u16* Gs = (u16*)smem;                   // [64][136]
    #pragma unroll
    for (int g = 0; g < 3; ++g) {
        __syncthreads();
        #pragma unroll
        for (int mt = 0; mt < 2; ++mt)
            #pragma unroll
            for (int nt = 0; nt < 2; ++nt) {
                int ch = nh*32 + nt*16 + l15;
                #pragma unroll
                for (int i = 0; i < 4; ++i) {
                    int row = mh*32 + mt*16 + qd4*4 + i;
                    Gs[row*136 + ch] = f2b(fmaxf(acc[g][mt][nt][i] + bias[g][nt], 0.f));
                }
            }
        __syncthreads();

        {
            int r = tid >> 3, pp = tid & 7;
            const char* rp = (const char*)Gs + r*272 + pp*32;
            float ssum = 0.f;
            #pragma unroll
            for (int t2 = 0; t2 < 2; ++t2) {
                uint4 u = *(const uint4*)(rp + t2*16);
                float x;
                x = bits2f(u.x << 16); ssum += x*x;  x = bits2f(u.x & 0xffff0000u); ssum += x*x;
                x = bits2f(u.y << 16); ssum += x*x;  x = bits2f(u.y & 0xffff0000u); ssum += x*x;
                x = bits2f(u.z << 16); ssum += x*x;  x = bits2f(u.z & 0xffff0000u); ssum += x*x;
                x = bits2f(u.w << 16); ssum += x*x;  x = bits2f(u.w & 0xffff0000u); ssum += x*x;
            }
            ssum += __shfl_xor(ssum, 1);
            ssum += __shfl_xor(ssum, 2);
            ssum += __shfl_xor(ssum, 4);
            if (pp == 0) {
                float inv = 1.f / (sqrtf(ssum) + 1e-13f);
                int gr = gR0 + r;
                int b = gr >> 8, pos = gr & 255;
                if (pos < 208)      invnd[(g*B_ + b)*208 + pos] = inv;
                else if (pos < 238) invnq[(g*B_ + b)*32 + (pos - 208)] = inv;
            }
        }
        #pragma unroll
        for (int i = 0; i < 2; ++i) {
            int idx = tid + i*512;
            int r = idx >> 4, c16 = idx & 15;
            uint4 v = *(const uint4*)((const char*)Gs + r*272 + c16*16);
            int gr = gR0 + r;
            int b = gr >> 8, pos = gr & 255;
            if (pos < 208)      *(uint4*)(dg + ((g*B_ + b)*208 + pos)*128 + c16*8) = v;
            else if (pos < 238) *(uint4*)(qg + ((g*B_ + b)*32 + (pos - 208))*128 + c16*8) = v;
        }
    }
}

// ---------------------------------------------------------------------------
// Pool (R9, banked): R3 body, grid split by qi (3,128,3) = 1152 blocks;
// af straight from L2-hot dg. Bit-exact vs R3 (see R9 notes).
// ---------------------------------------------------------------------------
__global__ __launch_bounds__(256, 4) void pool_kernel(
    const u16* __restrict__ qg, const u16* __restrict__ dg,
    const float* __restrict__ invnq, const float* __restrict__ invnd,
    const int* __restrict__ qtok, const int* __restrict__ dtok,
    float* __restrict__ feats)
{
    __shared__ float pk[32*12];                    // 1536 B
    __shared__ float invqA[32];
    __shared__ float qmA[32];
    __shared__ __align__(16) float invd[208];

    const int tid = threadIdx.x;
    const int b = blockIdx.y, dj = blockIdx.x, qi = blockIdx.z;
    const int wv = tid >> 6, lane = tid & 63;
    const int l15 = lane & 15, qd4 = lane >> 4;

    if (tid < 208) {
        float v = invnd[(dj*B_ + b)*208 + tid];
        bool ok = (tid < Dn) && (dtok[b*Dn + tid] > 0);
        invd[tid] = ok ? v : (-fabsf(v) - 1.0f);   // strictly negative if masked
    }
    if (tid < 32) {
        float v = invnq[(qi*B_ + b)*32 + tid];
        bool ok = (tid < Qn) && (qtok[b*Qn + tid] > 0);
        invqA[tid] = ok ? v : 0.f;
        qmA[tid] = ok ? 1.f : 0.f;
    }
    for (int i = tid; i < 32*12; i += 256) pk[i] = 0.f;
    __syncthreads();

    // chain constants C_k = exp(10*(mu_k + mu_{k+1})), mu: 0.9,0.7,...,-0.9
    const float CkR[9] = {8886110.5f, 162754.79f, 2980.958f, 54.598150f, 1.0f,
                          0.018315639f, 3.3546263e-4f, 6.1442124e-6f, 1.1253517e-7f};

    {
        short8 qf[2][4];
        float vq[2];
        #pragma unroll
        for (int qt = 0; qt < 2; ++qt) {
            vq[qt] = invqA[qt*16 + l15];
            #pragma unroll
            for (int ks = 0; ks < 4; ++ks)
                qf[qt][ks] = *(const short8*)(qg + ((qi*B_ + b)*32 + qt*16 + l15)*128 + ks*32 + qd4*8);
        }
        float pkl[2][11];
        #pragma unroll
        for (int qt = 0; qt < 2; ++qt)
            #pragma unroll
            for (int k = 0; k < 11; ++k) pkl[qt][k] = 0.f;

        const u16* dbase = dg + (size_t)(dj*B_ + b)*208*128;
        for (int t = wv; t < 13; t += 4) {
            short8 af[4];
            #pragma unroll
            for (int ks = 0; ks < 4; ++ks)
                af[ks] = *(const short8*)(dbase + (t*16 + l15)*128 + ks*32 + qd4*8);
            floatx4 acc[2];
            acc[0] = (floatx4){0.f,0.f,0.f,0.f};
            acc[1] = (floatx4){0.f,0.f,0.f,0.f};
            #pragma unroll
            for (int ks = 0; ks < 4; ++ks)
                #pragma unroll
                for (int qt = 0; qt < 2; ++qt)
                    acc[qt] = __builtin_amdgcn_mfma_f32_16x16x32_bf16(af[ks], qf[qt][ks], acc[qt], 0, 0, 0);
            floatx4 iv4 = *(const floatx4*)(invd + t*16 + qd4*4);
            #pragma unroll
            for (int qt = 0; qt < 2; ++qt)
                #pragma unroll
                for (int i = 0; i < 4; ++i) {
                    float cs = acc[qt][i] * vq[qt] * iv4[i];
                    cs = (cs > 0.f) ? cs : 2.0f;   // masked/zero -> all kernels ~0
                    float t0 = cs - 1.0f;
                    float u  = cs - 0.9f;
                    float s0 = __expf(-500000.f * t0 * t0);
                    float e  = __expf(-50.f * u * u);
                    float rr = __expf(-20.f * cs);
                    pkl[qt][0] += s0;
                    pkl[qt][1] += e;
                    #pragma unroll
                    for (int kk = 0; kk < 9; ++kk) {
                        e = e * rr * CkR[kk];
                        pkl[qt][2 + kk] += e;
                    }
                }
        }
        #pragma unroll
        for (int qt = 0; qt < 2; ++qt)
            #pragma unroll
            for (int k = 0; k < 11; ++k) {
                float v = pkl[qt][k];
                v += __shfl_xor(v, 16);
                v += __shfl_xor(v, 32);
                if (qd4 == 0) atomicAdd(&pk[(qt*16 + l15)*12 + k], v);
            }
    }
    __syncthreads();

    if (tid < 11) {
        int k = tid;
        float s = 0.f;
        for (int q = 0; q < Qn; ++q)
            s += qmA[q] * 0.01f * __logf(fmaxf(pk[q*12 + k], 1e-10f));
        feats[(b*9 + qi*3 + dj)*11 + k] = s;
    }
}

// ---------------------------------------------------------------------------
__global__ void final_kernel(const float* __restrict__ feats,
                             const float* __restrict__ dw,
                             float* __restrict__ out) {
    int b = threadIdx.x;
    if (b < B_) {
        float s = 0.f;
        for (int f = 0; f < 99; ++f) s += feats[b*99 + f] * dw[f];
        out[b] = s;
    }
}

extern "C" void kernel_launch(void* const* d_in, const int* in_sizes, int n_in,
                              void* d_out, int out_size, void* d_ws, size_t ws_size,
                              hipStream_t stream) {
    const int*   qtok = (const int*)d_in[0];
    const int*   dtok = (const int*)d_in[1];
    const float* emb  = (const float*)d_in[2];
    const float* w1   = (const float*)d_in[3];
    const float* w2   = (const float*)d_in[4];
    const float* w3   = (const float*)d_in[5];
    const float* b1   = (const float*)d_in[6];
    const float* b2   = (const float*)d_in[7];
    const float* b3   = (const float*)d_in[8];
    const float* dw   = (const float*)d_in[9];
    float* out = (float*)d_out;

    char* w = (char*)d_ws;
    u16*   Wt3   = (u16*)w;                      // 491,520 B
    u16*   qg    = (u16*)(w + 491520);           // 3*128*32*128*2  = 3,145,728
    u16*   dgm   = (u16*)(w + 3637248);          // 3*128*208*128*2 = 20,447,232
    float* invq_ = (float*)(w + 24084480);       // 49,152
    float* invd_ = (float*)(w + 24133632);       // 319,488
    float* feats = (float*)(w + 24453120);       // 50,688 -> total 24,503,808

    prep_kernel<<<dim3(8, B_), 256, 0, stream>>>(w1, w2, w3, Wt3);

    conv_kernel<<<dim3(512), 512, 0, stream>>>(
        qtok, dtok, emb, Wt3, b1, b2, b3, qg, dgm, invq_, invd_);

    pool_kernel<<<dim3(3, B_, 3), 256, 0, stream>>>(qg, dgm, invq_, invd_, qtok, dtok, feats);

    final_kernel<<<1, 128, 0, stream>>>(feats, dw, out);
}

// Round 11
// 160.620 us; speedup vs baseline: 1.0630x; 1.0630x over previous
//
#include <hip/hip_runtime.h>
#include <hip/hip_bf16.h>
#include <math.h>

#define B_   128
#define Qn   30
#define Dn   200
#define En   300

typedef __attribute__((ext_vector_type(8))) short short8;
typedef __attribute__((ext_vector_type(4))) float floatx4;
typedef unsigned int u32;
typedef unsigned short u16;

static __device__ __forceinline__ u16 f2b(float x) {   // fp32 -> bf16 RNE
    union { float f; u32 u; } v; v.f = x;
    u32 r = v.u + 0x7FFFu + ((v.u >> 16) & 1u);
    return (u16)(r >> 16);
}
static __device__ __forceinline__ float bits2f(u32 u) {
    union { u32 u2; float f; } v; v.u2 = u; return v.f;
}

// asm load: issues at the program point; the compiler cannot sink it.
// Completion is OUR job: counted s_waitcnt vmcnt(N) + sched_barrier(0).
static __device__ __forceinline__ short8 gload16(const u16* p) {
    short8 r;
    asm volatile("global_load_dwordx4 %0, %1, off" : "=&v"(r) : "v"(p));
    return r;
}

#define MFMA __builtin_amdgcn_mfma_f32_16x16x32_bf16

// ---------------------------------------------------------------------------
// prep: weight permute ONLY. ks-major: one K-slice = contiguous 48 KB:
//   Wt3[ks 10][ g1 j0 (8 chunks) | g2 j0,j1 (16) | g3 j0..j2 (24) ] x 1KB
// ---------------------------------------------------------------------------
__global__ void prep_kernel(
    const float* __restrict__ w1, const float* __restrict__ w2, const float* __restrict__ w3,
    u16* __restrict__ Wt3)
{
    int p = (blockIdx.x*128 + blockIdx.y)*256 + threadIdx.x;
    if (p >= 245760) return;
    int ks = p / 24576;
    int r  = p - ks*24576;
    int g, rr;
    if (r < 4096)        { g = 0; rr = r;         }
    else if (r < 12288)  { g = 1; rr = r - 4096;  }
    else                 { g = 2; rr = r - 12288; }
    int j  = rr >> 12;
    int r2 = rr & 4095;
    int nt  = r2 >> 9;
    int q4  = (r2 >> 7) & 3;
    int c16 = (r2 >> 3) & 15;
    int k8  = r2 & 7;
    int ch = nt*16 + c16;
    int e  = ks*32 + q4*8 + k8;
    float v = 0.f;
    if (e < En) {
        if (g == 0)      v = w1[ch*En + e];
        else if (g == 1) v = w2[(ch*En + e)*2 + j];
        else             v = w3[(ch*En + e)*3 + j];
    }
    Wt3[p] = f2b(v);
}

// ---------------------------------------------------------------------------
// Fused conv: R4-EXACT (banked ~35 us). B register-direct from L2-resident
// Wt3 with the COMPILER's schedule (R10's asm pipeline regressed to 45.7 —
// the compiler already interleaves the 6 independent load streams with
// MFMAs across K-slices; rigid fences outlaw that). No K-loop barriers;
// split A-gather with issue-early K-hi registers; 512-thread norms.
// ---------------------------------------------------------------------------
__global__ __launch_bounds__(512, 4) void conv_kernel(
    const int* __restrict__ qtok, const int* __restrict__ dtok,
    const float* __restrict__ emb,
    const u16* __restrict__ Wt3,
    const float* __restrict__ b1, const float* __restrict__ b2, const float* __restrict__ b3,
    u16* __restrict__ qg, u16* __restrict__ dg,
    float* __restrict__ invnq, float* __restrict__ invnd)
{
    __shared__ __align__(16) char smem[43560];   // As [66][656] + toks[66]
    char* As  = smem;
    int*  toks = (int*)(smem + 43296);

    const int tile = blockIdx.x;
    const int tid = threadIdx.x;
    const int wv = tid >> 6, lane = tid & 63;
    const int l15 = lane & 15, qd4 = lane >> 4;
    const int mh = wv >> 2, nh = wv & 3;
    const int gR0 = tile*64;

    if (tid < 66) {
        int gr = gR0 + tid;
        int t = -1;
        if (gr < 32768) {
            int b = gr >> 8, pos = gr & 255;
            if (pos < Dn) t = dtok[b*Dn + pos];
            else if (pos >= 208 && pos < 238) t = qtok[b*Qn + (pos - 208)];
        }
        toks[tid] = t;
    }
    __syncthreads();

    #pragma unroll
    for (int i = 0; i < 6; ++i) {
        int idx = tid + i*512;
        if (idx < 2640) {
            int r = idx / 40, c4 = idx - r*40;
            int t = toks[r];
            u16 o0=0,o1=0,o2=0,o3=0;
            if (t >= 0) {
                float4 v = *(const float4*)(emb + t*En + c4*4);
                o0=f2b(v.x); o1=f2b(v.y); o2=f2b(v.z); o3=f2b(v.w);
            }
            u16* pdst = (u16*)(As + r*656 + c4*8);
            pdst[0]=o0; pdst[1]=o1; pdst[2]=o2; pdst[3]=o3;
        }
    }

    float bias[3][2];
    #pragma unroll
    for (int nt = 0; nt < 2; ++nt) {
        int ch = nh*32 + nt*16 + l15;
        bias[0][nt] = b1[ch];
        bias[1][nt] = b2[ch];
        bias[2][nt] = b3[ch];
    }

    floatx4 acc[3][2][2];
    #pragma unroll
    for (int g = 0; g < 3; ++g)
        #pragma unroll
        for (int mt = 0; mt < 2; ++mt)
            #pragma unroll
            for (int nt = 0; nt < 2; ++nt)
                acc[g][mt][nt] = (floatx4){0.f,0.f,0.f,0.f};

    __syncthreads();                        // A K-lo ready

    float4 hf[6];
    #pragma unroll
    for (int i = 0; i < 6; ++i) {
        int idx = tid + i*512;
        const float* p = emb;               // safe dummy
        if (idx < 2640) {
            int r = idx / 40, c = idx - r*40;
            int t = toks[r];
            if (t >= 0 && c < 35) p = emb + t*En + (40 + c)*4;
        }
        hf[i] = *(const float4*)p;
    }

    #pragma unroll 1
    for (int ks = 0; ks < 5; ++ks) {
        short8 af[2][3];
        #pragma unroll
        for (int mt = 0; mt < 2; ++mt)
            #pragma unroll
            for (int j = 0; j < 3; ++j)
                af[mt][j] = *(const short8*)(As + (mh*32 + mt*16 + l15 + j)*656 + ks*64 + qd4*16);
        const u16* Wks = Wt3 + ks*24576;
        #pragma unroll
        for (int g = 0; g < 3; ++g) {
            const int cbW = (g == 0) ? 0 : (g == 1) ? 4096 : 12288;
            #pragma unroll
            for (int j = 0; j <= g; ++j) {
                const u16* bb = Wks + cbW + (j*8 + nh*2)*512 + lane*8;
                short8 w0  = *(const short8*)(bb);
                short8 w1v = *(const short8*)(bb + 512);
                #pragma unroll
                for (int mt = 0; mt < 2; ++mt) {
                    acc[g][mt][0] = MFMA(af[mt][j], w0,  acc[g][mt][0], 0, 0, 0);
                    acc[g][mt][1] = MFMA(af[mt][j], w1v, acc[g][mt][1], 0, 0, 0);
                }
            }
        }
    }

    #pragma unroll
    for (int i = 0; i < 6; ++i) {
        int idx = tid + i*512;
        if (idx < 2640) {
            int r = idx / 40, c = idx - r*40;
            int t = toks[r];
            bool ok = (t >= 0) && (c < 35);
            u16 o0=0,o1=0,o2=0,o3=0;
            if (ok) { o0=f2b(hf[i].x); o1=f2b(hf[i].y); o2=f2b(hf[i].z); o3=f2b(hf[i].w); }
            u16* pdst = (u16*)(As + r*656 + (40 + c)*8);
            pdst[0]=o0; pdst[1]=o1; pdst[2]=o2; pdst[3]=o3;
        }
    }
    __syncthreads();                        // K-hi ready

    #pragma unroll 1
    for (int ks = 5; ks < 10; ++ks) {
        short8 af[2][3];
        #pragma unroll
        for (int mt = 0; mt < 2; ++mt)
            #pragma unroll
            for (int j = 0; j < 3; ++j)
                af[mt][j] = *(const short8*)(As + (mh*32 + mt*16 + l15 + j)*656 + ks*64 + qd4*16);
        const u16* Wks = Wt3 + ks*24576;
        #pragma unroll
        for (int g = 0; g < 3; ++g) {
            const int cbW = (g == 0) ? 0 : (g == 1) ? 4096 : 12288;
            #pragma unroll
            for (int j = 0; j <= g; ++j) {
                const u16* bb = Wks + cbW + (j*8 + nh*2)*512 + lane*8;
                short8 w0  = *(const short8*)(bb);
                short8 w1v = *(const short8*)(bb + 512);
                #pragma unroll
                for (int mt = 0; mt < 2; ++mt) {
                    acc[g][mt][0] = MFMA(af[mt][j], w0,  acc[g][mt][0], 0, 0, 0);
                    acc[g][mt][1] = MFMA(af[mt][j], w1v, acc[g][mt][1], 0, 0, 0);
                }
            }
        }
    }

    u16* Gs = (u16*)smem;                   // [64][136]
    #pragma unroll
    for (int g = 0; g < 3; ++g) {
        __syncthreads();
        #pragma unroll
        for (int mt = 0; mt < 2; ++mt)
            #pragma unroll
            for (int nt = 0; nt < 2; ++nt) {
                int ch = nh*32 + nt*16 + l15;
                #pragma unroll
                for (int i = 0; i < 4; ++i) {
                    int row = mh*32 + mt*16 + qd4*4 + i;
                    Gs[row*136 + ch] = f2b(fmaxf(acc[g][mt][nt][i] + bias[g][nt], 0.f));
                }
            }
        __syncthreads();

        {
            int r = tid >> 3, pp = tid & 7;
            const char* rp = (const char*)Gs + r*272 + pp*32;
            float ssum = 0.f;
            #pragma unroll
            for (int t2 = 0; t2 < 2; ++t2) {
                uint4 u = *(const uint4*)(rp + t2*16);
                float x;
                x = bits2f(u.x << 16); ssum += x*x;  x = bits2f(u.x & 0xffff0000u); ssum += x*x;
                x = bits2f(u.y << 16); ssum += x*x;  x = bits2f(u.y & 0xffff0000u); ssum += x*x;
                x = bits2f(u.z << 16); ssum += x*x;  x = bits2f(u.z & 0xffff0000u); ssum += x*x;
                x = bits2f(u.w << 16); ssum += x*x;  x = bits2f(u.w & 0xffff0000u); ssum += x*x;
            }
            ssum += __shfl_xor(ssum, 1);
            ssum += __shfl_xor(ssum, 2);
            ssum += __shfl_xor(ssum, 4);
            if (pp == 0) {
                float inv = 1.f / (sqrtf(ssum) + 1e-13f);
                int gr = gR0 + r;
                int b = gr >> 8, pos = gr & 255;
                if (pos < 208)      invnd[(g*B_ + b)*208 + pos] = inv;
                else if (pos < 238) invnq[(g*B_ + b)*32 + (pos - 208)] = inv;
            }
        }
        #pragma unroll
        for (int i = 0; i < 2; ++i) {
            int idx = tid + i*512;
            int r = idx >> 4, c16 = idx & 15;
            uint4 v = *(const uint4*)((const char*)Gs + r*272 + c16*16);
            int gr = gR0 + r;
            int b = gr >> 8, pos = gr & 255;
            if (pos < 208)      *(uint4*)(dg + ((g*B_ + b)*208 + pos)*128 + c16*8) = v;
            else if (pos < 238) *(uint4*)(qg + ((g*B_ + b)*32 + (pos - 208))*128 + c16*8) = v;
        }
    }
}

// ---------------------------------------------------------------------------
// Pool, R11: R9 grid/body (qi split, L2-direct dg) + asm issue-all-upfront
// loads with counted vmcnt. All 8 qf + 16 af loads issued right after the
// prologue barrier (compiler cannot sink asm — R6/R7 showed it sinks source
// loads, leaving ~300-cyc stalls per iter in a VALU-heavy loop). Per-tile
// vmcnt(12/8/4/0) + sched_barrier(0) (rule #18) before its MFMAs; each
// iter's exp-chain (~400 cyc VALU) then hides the NEXT iters' loads.
// wv>=1 waves clamp t3 to a valid row and skip its exp/reduce (uniform
// branch; dangling loads retire harmlessly). MFMA/exp/reduce order per
// contribution identical to R9 => bit-identical results.
// ---------------------------------------------------------------------------
__global__ __launch_bounds__(256, 2) void pool_kernel(
    const u16* __restrict__ qg, const u16* __restrict__ dg,
    const float* __restrict__ invnq, const float* __restrict__ invnd,
    const int* __restrict__ qtok, const int* __restrict__ dtok,
    float* __restrict__ feats)
{
    __shared__ float pk[32*12];                    // 1536 B
    __shared__ float invqA[32];
    __shared__ float qmA[32];
    __shared__ __align__(16) float invd[208];

    const int tid = threadIdx.x;
    const int b = blockIdx.y, dj = blockIdx.x, qi = blockIdx.z;
    const int wv = tid >> 6, lane = tid & 63;
    const int l15 = lane & 15, qd4 = lane >> 4;

    if (tid < 208) {
        float v = invnd[(dj*B_ + b)*208 + tid];
        bool ok = (tid < Dn) && (dtok[b*Dn + tid] > 0);
        invd[tid] = ok ? v : (-fabsf(v) - 1.0f);   // strictly negative if masked
    }
    if (tid < 32) {
        float v = invnq[(qi*B_ + b)*32 + tid];
        bool ok = (tid < Qn) && (qtok[b*Qn + tid] > 0);
        invqA[tid] = ok ? v : 0.f;
        qmA[tid] = ok ? 1.f : 0.f;
    }
    for (int i = tid; i < 32*12; i += 256) pk[i] = 0.f;
    __syncthreads();                        // drains prologue vmem: vmcnt==0 here

    // chain constants C_k = exp(10*(mu_k + mu_{k+1})), mu: 0.9,0.7,...,-0.9
    const float CkR[9] = {8886110.5f, 162754.79f, 2980.958f, 54.598150f, 1.0f,
                          0.018315639f, 3.3546263e-4f, 6.1442124e-6f, 1.1253517e-7f};

    const u16* qbase = qg + (size_t)((qi*B_ + b)*32)*128 + l15*128 + qd4*8;
    const u16* dbase = dg + (size_t)(dj*B_ + b)*208*128 + l15*128 + qd4*8;
    const int t0 = wv, t1 = wv + 4, t2 = wv + 8;
    const int t3 = (wv == 0) ? 12 : 11;     // clamped for wv>=1 (discarded)

    // ---- issue order defines vmcnt counts: qf(8), af0(4), af1(4), af2(4), af3(4)
    short8 q00 = gload16(qbase + 0*32);
    short8 q01 = gload16(qbase + 1*32);
    short8 q02 = gload16(qbase + 2*32);
    short8 q03 = gload16(qbase + 3*32);
    short8 q10 = gload16(qbase + 16*128 + 0*32);
    short8 q11 = gload16(qbase + 16*128 + 1*32);
    short8 q12 = gload16(qbase + 16*128 + 2*32);
    short8 q13 = gload16(qbase + 16*128 + 3*32);
    short8 a00 = gload16(dbase + t0*2048 + 0*32);
    short8 a01 = gload16(dbase + t0*2048 + 1*32);
    short8 a02 = gload16(dbase + t0*2048 + 2*32);
    short8 a03 = gload16(dbase + t0*2048 + 3*32);
    short8 a10 = gload16(dbase + t1*2048 + 0*32);
    short8 a11 = gload16(dbase + t1*2048 + 1*32);
    short8 a12 = gload16(dbase + t1*2048 + 2*32);
    short8 a13 = gload16(dbase + t1*2048 + 3*32);
    short8 a20 = gload16(dbase + t2*2048 + 0*32);
    short8 a21 = gload16(dbase + t2*2048 + 1*32);
    short8 a22 = gload16(dbase + t2*2048 + 2*32);
    short8 a23 = gload16(dbase + t2*2048 + 3*32);
    short8 a30 = gload16(dbase + t3*2048 + 0*32);
    short8 a31 = gload16(dbase + t3*2048 + 1*32);
    short8 a32 = gload16(dbase + t3*2048 + 2*32);
    short8 a33 = gload16(dbase + t3*2048 + 3*32);

    float vq0 = invqA[l15], vq1 = invqA[16 + l15];

    float pkl[2][11];
    #pragma unroll
    for (int qt = 0; qt < 2; ++qt)
        #pragma unroll
        for (int k = 0; k < 11; ++k) pkl[qt][k] = 0.f;

    // per-tile body; VMSTR counts the loads NOT yet needed (issue order above)
    #define PITER(A0, A1, A2, A3, TT, VMSTR)                                  \
    {                                                                         \
        asm volatile("s_waitcnt vmcnt(" VMSTR ")" ::: "memory");              \
        __builtin_amdgcn_sched_barrier(0);                                    \
        floatx4 ac0 = (floatx4){0.f,0.f,0.f,0.f};                             \
        floatx4 ac1 = (floatx4){0.f,0.f,0.f,0.f};                             \
        ac0 = MFMA(A0, q00, ac0, 0,0,0); ac1 = MFMA(A0, q10, ac1, 0,0,0);     \
        ac0 = MFMA(A1, q01, ac0, 0,0,0); ac1 = MFMA(A1, q11, ac1, 0,0,0);     \
        ac0 = MFMA(A2, q02, ac0, 0,0,0); ac1 = MFMA(A2, q12, ac1, 0,0,0);     \
        ac0 = MFMA(A3, q03, ac0, 0,0,0); ac1 = MFMA(A3, q13, ac1, 0,0,0);     \
        floatx4 iv4 = *(const floatx4*)(invd + (TT)*16 + qd4*4);              \
        _Pragma("unroll")                                                     \
        for (int i = 0; i < 4; ++i) {                                         \
            float cs = ac0[i] * vq0 * iv4[i];                                 \
            cs = (cs > 0.f) ? cs : 2.0f;                                      \
            float tt0 = cs - 1.0f, uu = cs - 0.9f;                            \
            float s0 = __expf(-500000.f * tt0 * tt0);                         \
            float e  = __expf(-50.f * uu * uu);                               \
            float rr = __expf(-20.f * cs);                                    \
            pkl[0][0] += s0; pkl[0][1] += e;                                  \
            _Pragma("unroll")                                                 \
            for (int kk = 0; kk < 9; ++kk) {                                  \
                e = e * rr * CkR[kk]; pkl[0][2 + kk] += e;                    \
            }                                                                 \
        }                                                                     \
        _Pragma("unroll")                                                     \
        for (int i = 0; i < 4; ++i) {                                         \
            float cs = ac1[i] * vq1 * iv4[i];                                 \
            cs = (cs > 0.f) ? cs : 2.0f;                                      \
            float tt0 = cs - 1.0f, uu = cs - 0.9f;                            \
            float s0 = __expf(-500000.f * tt0 * tt0);                         \
            float e  = __expf(-50.f * uu * uu);                               \
            float rr = __expf(-20.f * cs);                                    \
            pkl[1][0] += s0; pkl[1][1] += e;                                  \
            _Pragma("unroll")                                                 \
            for (int kk = 0; kk < 9; ++kk) {                                  \
                e = e * rr * CkR[kk]; pkl[1][2 + kk] += e;                    \
            }                                                                 \
        }                                                                     \
    }

    PITER(a00, a01, a02, a03, t0, "12")
    PITER(a10, a11, a12, a13, t1, "8")
    PITER(a20, a21, a22, a23, t2, "4")
    if (wv == 0) { PITER(a30, a31, a32, a33, t3, "0") }
    #undef PITER

    #pragma unroll
    for (int qt = 0; qt < 2; ++qt)
        #pragma unroll
        for (int k = 0; k < 11; ++k) {
            float v = pkl[qt][k];
            v += __shfl_xor(v, 16);
            v += __shfl_xor(v, 32);
            if (qd4 == 0) atomicAdd(&pk[(qt*16 + l15)*12 + k], v);
        }
    __syncthreads();

    if (tid < 11) {
        int k = tid;
        float s = 0.f;
        for (int q = 0; q < Qn; ++q)
            s += qmA[q] * 0.01f * __logf(fmaxf(pk[q*12 + k], 1e-10f));
        feats[(b*9 + qi*3 + dj)*11 + k] = s;
    }
}

// ---------------------------------------------------------------------------
__global__ void final_kernel(const float* __restrict__ feats,
                             const float* __restrict__ dw,
                             float* __restrict__ out) {
    int b = threadIdx.x;
    if (b < B_) {
        float s = 0.f;
        for (int f = 0; f < 99; ++f) s += feats[b*99 + f] * dw[f];
        out[b] = s;
    }
}

extern "C" void kernel_launch(void* const* d_in, const int* in_sizes, int n_in,
                              void* d_out, int out_size, void* d_ws, size_t ws_size,
                              hipStream_t stream) {
    const int*   qtok = (const int*)d_in[0];
    const int*   dtok = (const int*)d_in[1];
    const float* emb  = (const float*)d_in[2];
    const float* w1   = (const float*)d_in[3];
    const float* w2   = (const float*)d_in[4];
    const float* w3   = (const float*)d_in[5];
    const float* b1   = (const float*)d_in[6];
    const float* b2   = (const float*)d_in[7];
    const float* b3   = (const float*)d_in[8];
    const float* dw   = (const float*)d_in[9];
    float* out = (float*)d_out;

    char* w = (char*)d_ws;
    u16*   Wt3   = (u16*)w;                      // 491,520 B
    u16*   qg    = (u16*)(w + 491520);           // 3*128*32*128*2  = 3,145,728
    u16*   dgm   = (u16*)(w + 3637248);          // 3*128*208*128*2 = 20,447,232
    float* invq_ = (float*)(w + 24084480);       // 49,152
    float* invd_ = (float*)(w + 24133632);       // 319,488
    float* feats = (float*)(w + 24453120);       // 50,688 -> total 24,503,808

    prep_kernel<<<dim3(8, B_), 256, 0, stream>>>(w1, w2, w3, Wt3);

    conv_kernel<<<dim3(512), 512, 0, stream>>>(
        qtok, dtok, emb, Wt3, b1, b2, b3, qg, dgm, invq_, invd_);

    pool_kernel<<<dim3(3, B_, 3), 256, 0, stream>>>(qg, dgm, invq_, invd_, qtok, dtok, feats);

    final_kernel<<<1, 128, 0, stream>>>(feats, dw, out);
}

// Round 12
// 159.497 us; speedup vs baseline: 1.0704x; 1.0070x over previous
//
#include <hip/hip_runtime.h>
#include <hip/hip_bf16.h>
#include <math.h>

#define B_   128
#define Qn   30
#define Dn   200
#define En   300

typedef __attribute__((ext_vector_type(8))) short short8;
typedef __attribute__((ext_vector_type(4))) float floatx4;
typedef unsigned int u32;
typedef unsigned short u16;

static __device__ __forceinline__ u16 f2b(float x) {   // fp32 -> bf16 RNE
    union { float f; u32 u; } v; v.f = x;
    u32 r = v.u + 0x7FFFu + ((v.u >> 16) & 1u);
    return (u16)(r >> 16);
}
static __device__ __forceinline__ float bits2f(u32 u) {
    union { u32 u2; float f; } v; v.u2 = u; return v.f;
}

// asm load: issues at the program point; the compiler cannot sink it.
// Completion is OUR job: counted s_waitcnt vmcnt(N) + sched_barrier(0).
static __device__ __forceinline__ short8 gload16(const u16* p) {
    short8 r;
    asm volatile("global_load_dwordx4 %0, %1, off" : "=&v"(r) : "v"(p));
    return r;
}

#define MFMA __builtin_amdgcn_mfma_f32_16x16x32_bf16

// ---------------------------------------------------------------------------
// prep: weight permute ONLY. ks-major: one K-slice = contiguous 48 KB:
//   Wt3[ks 10][ g1 j0 (8 chunks) | g2 j0,j1 (16) | g3 j0..j2 (24) ] x 1KB
// ---------------------------------------------------------------------------
__global__ void prep_kernel(
    const float* __restrict__ w1, const float* __restrict__ w2, const float* __restrict__ w3,
    u16* __restrict__ Wt3)
{
    int p = (blockIdx.x*128 + blockIdx.y)*256 + threadIdx.x;
    if (p >= 245760) return;
    int ks = p / 24576;
    int r  = p - ks*24576;
    int g, rr;
    if (r < 4096)        { g = 0; rr = r;         }
    else if (r < 12288)  { g = 1; rr = r - 4096;  }
    else                 { g = 2; rr = r - 12288; }
    int j  = rr >> 12;
    int r2 = rr & 4095;
    int nt  = r2 >> 9;
    int q4  = (r2 >> 7) & 3;
    int c16 = (r2 >> 3) & 15;
    int k8  = r2 & 7;
    int ch = nt*16 + c16;
    int e  = ks*32 + q4*8 + k8;
    float v = 0.f;
    if (e < En) {
        if (g == 0)      v = w1[ch*En + e];
        else if (g == 1) v = w2[(ch*En + e)*2 + j];
        else             v = w3[(ch*En + e)*3 + j];
    }
    Wt3[p] = f2b(v);
}

// ---------------------------------------------------------------------------
// Fused conv, R12: R4 structure with the wave->output remap that ELIMINATES
// intra-block B duplication. Old: wave (mh,nh) covered 32 rows x 32 ch;
// mh=0/1 pairs loaded IDENTICAL B fragments (96 KB/block/ks; 491 MB L2
// aggregate ~ 14 us). New: wave wv covers ALL 64 rows x 16-ch strip nt=wv:
// 48 KB/block/ks distinct (245 MB, ~7 us) and each B fragment feeds 4 MFMAs
// (was 2). Loop order ks -> j -> g(>=j) -> mt keeps each output's
// contribution sequence (ks, then j ascending) identical => bit-identical.
// af loaded per-j (4 live short8) to stay under the 128-VGPR cap of
// launch_bounds(512,4) (R10 lesson: VGPR 128+ halves occupancy).
// ---------------------------------------------------------------------------
__global__ __launch_bounds__(512, 4) void conv_kernel(
    const int* __restrict__ qtok, const int* __restrict__ dtok,
    const float* __restrict__ emb,
    const u16* __restrict__ Wt3,
    const float* __restrict__ b1, const float* __restrict__ b2, const float* __restrict__ b3,
    u16* __restrict__ qg, u16* __restrict__ dg,
    float* __restrict__ invnq, float* __restrict__ invnd)
{
    __shared__ __align__(16) char smem[43560];   // As [66][656] + toks[66]
    char* As  = smem;
    int*  toks = (int*)(smem + 43296);

    const int tile = blockIdx.x;
    const int tid = threadIdx.x;
    const int wv = tid >> 6, lane = tid & 63;    // wv = 16-ch strip (nt)
    const int l15 = lane & 15, qd4 = lane >> 4;
    const int gR0 = tile*64;

    if (tid < 66) {
        int gr = gR0 + tid;
        int t = -1;
        if (gr < 32768) {
            int b = gr >> 8, pos = gr & 255;
            if (pos < Dn) t = dtok[b*Dn + pos];
            else if (pos >= 208 && pos < 238) t = qtok[b*Qn + (pos - 208)];
        }
        toks[tid] = t;
    }
    __syncthreads();

    // stage A K-lo: 66 rows x col4 0..39 (K elems 0..159) — all ks 0..4 reads
    #pragma unroll
    for (int i = 0; i < 6; ++i) {
        int idx = tid + i*512;
        if (idx < 2640) {
            int r = idx / 40, c4 = idx - r*40;
            int t = toks[r];
            u16 o0=0,o1=0,o2=0,o3=0;
            if (t >= 0) {
                float4 v = *(const float4*)(emb + t*En + c4*4);
                o0=f2b(v.x); o1=f2b(v.y); o2=f2b(v.z); o3=f2b(v.w);
            }
            u16* pdst = (u16*)(As + r*656 + c4*8);
            pdst[0]=o0; pdst[1]=o1; pdst[2]=o2; pdst[3]=o3;
        }
    }

    float bias[3];
    {
        int ch = wv*16 + l15;
        bias[0] = b1[ch];
        bias[1] = b2[ch];
        bias[2] = b3[ch];
    }

    floatx4 acc[3][4];                      // [gram][mt 16-row tile]
    #pragma unroll
    for (int g = 0; g < 3; ++g)
        #pragma unroll
        for (int mt = 0; mt < 4; ++mt)
            acc[g][mt] = (floatx4){0.f,0.f,0.f,0.f};

    __syncthreads();                        // A K-lo ready

    // K-hi loads (cols 160..319) issued into registers; fly under ks 0..4.
    float4 hf[6];
    #pragma unroll
    for (int i = 0; i < 6; ++i) {
        int idx = tid + i*512;
        const float* p = emb;               // safe dummy
        if (idx < 2640) {
            int r = idx / 40, c = idx - r*40;
            int t = toks[r];
            if (t >= 0 && c < 35) p = emb + t*En + (40 + c)*4;
        }
        hf[i] = *(const float4*)p;
    }

    #pragma unroll 1
    for (int ks = 0; ks < 5; ++ks) {
        const u16* Wks = Wt3 + ks*24576;
        #pragma unroll
        for (int j = 0; j < 3; ++j) {
            short8 afj[4];
            #pragma unroll
            for (int mt = 0; mt < 4; ++mt)
                afj[mt] = *(const short8*)(As + (mt*16 + l15 + j)*656 + ks*64 + qd4*16);
            #pragma unroll
            for (int g = 0; g < 3; ++g) {
                if (g < j) continue;
                const int cbW = (g == 0) ? 0 : (g == 1) ? 4096 : 12288;
                short8 wf = *(const short8*)(Wks + cbW + (j*8 + wv)*512 + lane*8);
                #pragma unroll
                for (int mt = 0; mt < 4; ++mt)
                    acc[g][mt] = MFMA(afj[mt], wf, acc[g][mt], 0, 0, 0);
            }
        }
    }

    // write K-hi into As (region untouched by ks 0..4 reads), one barrier
    #pragma unroll
    for (int i = 0; i < 6; ++i) {
        int idx = tid + i*512;
        if (idx < 2640) {
            int r = idx / 40, c = idx - r*40;
            int t = toks[r];
            bool ok = (t >= 0) && (c < 35);
            u16 o0=0,o1=0,o2=0,o3=0;
            if (ok) { o0=f2b(hf[i].x); o1=f2b(hf[i].y); o2=f2b(hf[i].z); o3=f2b(hf[i].w); }
            u16* pdst = (u16*)(As + r*656 + (40 + c)*8);
            pdst[0]=o0; pdst[1]=o1; pdst[2]=o2; pdst[3]=o3;
        }
    }
    __syncthreads();                        // K-hi ready

    #pragma unroll 1
    for (int ks = 5; ks < 10; ++ks) {
        const u16* Wks = Wt3 + ks*24576;
        #pragma unroll
        for (int j = 0; j < 3; ++j) {
            short8 afj[4];
            #pragma unroll
            for (int mt = 0; mt < 4; ++mt)
                afj[mt] = *(const short8*)(As + (mt*16 + l15 + j)*656 + ks*64 + qd4*16);
            #pragma unroll
            for (int g = 0; g < 3; ++g) {
                if (g < j) continue;
                const int cbW = (g == 0) ? 0 : (g == 1) ? 4096 : 12288;
                short8 wf = *(const short8*)(Wks + cbW + (j*8 + wv)*512 + lane*8);
                #pragma unroll
                for (int mt = 0; mt < 4; ++mt)
                    acc[g][mt] = MFMA(afj[mt], wf, acc[g][mt], 0, 0, 0);
            }
        }
    }

    // epilogue: per-gram Gs overlay on As; fully unrolled over g (rule #20);
    // norms across all 512 threads (8 lanes/row + shfl_xor).
    u16* Gs = (u16*)smem;                   // [64][136]
    #pragma unroll
    for (int g = 0; g < 3; ++g) {
        __syncthreads();
        {
            int ch = wv*16 + l15;
            #pragma unroll
            for (int mt = 0; mt < 4; ++mt)
                #pragma unroll
                for (int i = 0; i < 4; ++i) {
                    int row = mt*16 + qd4*4 + i;
                    Gs[row*136 + ch] = f2b(fmaxf(acc[g][mt][i] + bias[g], 0.f));
                }
        }
        __syncthreads();

        {
            int r = tid >> 3, pp = tid & 7;
            const char* rp = (const char*)Gs + r*272 + pp*32;
            float ssum = 0.f;
            #pragma unroll
            for (int t2 = 0; t2 < 2; ++t2) {
                uint4 u = *(const uint4*)(rp + t2*16);
                float x;
                x = bits2f(u.x << 16); ssum += x*x;  x = bits2f(u.x & 0xffff0000u); ssum += x*x;
                x = bits2f(u.y << 16); ssum += x*x;  x = bits2f(u.y & 0xffff0000u); ssum += x*x;
                x = bits2f(u.z << 16); ssum += x*x;  x = bits2f(u.z & 0xffff0000u); ssum += x*x;
                x = bits2f(u.w << 16); ssum += x*x;  x = bits2f(u.w & 0xffff0000u); ssum += x*x;
            }
            ssum += __shfl_xor(ssum, 1);
            ssum += __shfl_xor(ssum, 2);
            ssum += __shfl_xor(ssum, 4);
            if (pp == 0) {
                float inv = 1.f / (sqrtf(ssum) + 1e-13f);
                int gr = gR0 + r;
                int b = gr >> 8, pos = gr & 255;
                if (pos < 208)      invnd[(g*B_ + b)*208 + pos] = inv;
                else if (pos < 238) invnq[(g*B_ + b)*32 + (pos - 208)] = inv;
            }
        }
        #pragma unroll
        for (int i = 0; i < 2; ++i) {
            int idx = tid + i*512;
            int r = idx >> 4, c16 = idx & 15;
            uint4 v = *(const uint4*)((const char*)Gs + r*272 + c16*16);
            int gr = gR0 + r;
            int b = gr >> 8, pos = gr & 255;
            if (pos < 208)      *(uint4*)(dg + ((g*B_ + b)*208 + pos)*128 + c16*8) = v;
            else if (pos < 238) *(uint4*)(qg + ((g*B_ + b)*32 + (pos - 208))*128 + c16*8) = v;
        }
    }
}

// ---------------------------------------------------------------------------
// Pool (R11, banked): qi-split grid, L2-direct dg, asm issue-all-upfront
// loads + counted vmcnt per tile. Bit-identical contribution order.
// ---------------------------------------------------------------------------
__global__ __launch_bounds__(256, 2) void pool_kernel(
    const u16* __restrict__ qg, const u16* __restrict__ dg,
    const float* __restrict__ invnq, const float* __restrict__ invnd,
    const int* __restrict__ qtok, const int* __restrict__ dtok,
    float* __restrict__ feats)
{
    __shared__ float pk[32*12];                    // 1536 B
    __shared__ float invqA[32];
    __shared__ float qmA[32];
    __shared__ __align__(16) float invd[208];

    const int tid = threadIdx.x;
    const int b = blockIdx.y, dj = blockIdx.x, qi = blockIdx.z;
    const int wv = tid >> 6, lane = tid & 63;
    const int l15 = lane & 15, qd4 = lane >> 4;

    if (tid < 208) {
        float v = invnd[(dj*B_ + b)*208 + tid];
        bool ok = (tid < Dn) && (dtok[b*Dn + tid] > 0);
        invd[tid] = ok ? v : (-fabsf(v) - 1.0f);   // strictly negative if masked
    }
    if (tid < 32) {
        float v = invnq[(qi*B_ + b)*32 + tid];
        bool ok = (tid < Qn) && (qtok[b*Qn + tid] > 0);
        invqA[tid] = ok ? v : 0.f;
        qmA[tid] = ok ? 1.f : 0.f;
    }
    for (int i = tid; i < 32*12; i += 256) pk[i] = 0.f;
    __syncthreads();                        // drains prologue vmem: vmcnt==0 here

    // chain constants C_k = exp(10*(mu_k + mu_{k+1})), mu: 0.9,0.7,...,-0.9
    const float CkR[9] = {8886110.5f, 162754.79f, 2980.958f, 54.598150f, 1.0f,
                          0.018315639f, 3.3546263e-4f, 6.1442124e-6f, 1.1253517e-7f};

    const u16* qbase = qg + (size_t)((qi*B_ + b)*32)*128 + l15*128 + qd4*8;
    const u16* dbase = dg + (size_t)(dj*B_ + b)*208*128 + l15*128 + qd4*8;
    const int t0 = wv, t1 = wv + 4, t2 = wv + 8;
    const int t3 = (wv == 0) ? 12 : 11;     // clamped for wv>=1 (discarded)

    // ---- issue order defines vmcnt counts: qf(8), af0(4), af1(4), af2(4), af3(4)
    short8 q00 = gload16(qbase + 0*32);
    short8 q01 = gload16(qbase + 1*32);
    short8 q02 = gload16(qbase + 2*32);
    short8 q03 = gload16(qbase + 3*32);
    short8 q10 = gload16(qbase + 16*128 + 0*32);
    short8 q11 = gload16(qbase + 16*128 + 1*32);
    short8 q12 = gload16(qbase + 16*128 + 2*32);
    short8 q13 = gload16(qbase + 16*128 + 3*32);
    short8 a00 = gload16(dbase + t0*2048 + 0*32);
    short8 a01 = gload16(dbase + t0*2048 + 1*32);
    short8 a02 = gload16(dbase + t0*2048 + 2*32);
    short8 a03 = gload16(dbase + t0*2048 + 3*32);
    short8 a10 = gload16(dbase + t1*2048 + 0*32);
    short8 a11 = gload16(dbase + t1*2048 + 1*32);
    short8 a12 = gload16(dbase + t1*2048 + 2*32);
    short8 a13 = gload16(dbase + t1*2048 + 3*32);
    short8 a20 = gload16(dbase + t2*2048 + 0*32);
    short8 a21 = gload16(dbase + t2*2048 + 1*32);
    short8 a22 = gload16(dbase + t2*2048 + 2*32);
    short8 a23 = gload16(dbase + t2*2048 + 3*32);
    short8 a30 = gload16(dbase + t3*2048 + 0*32);
    short8 a31 = gload16(dbase + t3*2048 + 1*32);
    short8 a32 = gload16(dbase + t3*2048 + 2*32);
    short8 a33 = gload16(dbase + t3*2048 + 3*32);

    float vq0 = invqA[l15], vq1 = invqA[16 + l15];

    float pkl[2][11];
    #pragma unroll
    for (int qt = 0; qt < 2; ++qt)
        #pragma unroll
        for (int k = 0; k < 11; ++k) pkl[qt][k] = 0.f;

    // per-tile body; VMSTR counts the loads NOT yet needed (issue order above)
    #define PITER(A0, A1, A2, A3, TT, VMSTR)                                  \
    {                                                                         \
        asm volatile("s_waitcnt vmcnt(" VMSTR ")" ::: "memory");              \
        __builtin_amdgcn_sched_barrier(0);                                    \
        floatx4 ac0 = (floatx4){0.f,0.f,0.f,0.f};                             \
        floatx4 ac1 = (floatx4){0.f,0.f,0.f,0.f};                             \
        ac0 = MFMA(A0, q00, ac0, 0,0,0); ac1 = MFMA(A0, q10, ac1, 0,0,0);     \
        ac0 = MFMA(A1, q01, ac0, 0,0,0); ac1 = MFMA(A1, q11, ac1, 0,0,0);     \
        ac0 = MFMA(A2, q02, ac0, 0,0,0); ac1 = MFMA(A2, q12, ac1, 0,0,0);     \
        ac0 = MFMA(A3, q03, ac0, 0,0,0); ac1 = MFMA(A3, q13, ac1, 0,0,0);     \
        floatx4 iv4 = *(const floatx4*)(invd + (TT)*16 + qd4*4);              \
        _Pragma("unroll")                                                     \
        for (int i = 0; i < 4; ++i) {                                         \
            float cs = ac0[i] * vq0 * iv4[i];                                 \
            cs = (cs > 0.f) ? cs : 2.0f;                                      \
            float tt0 = cs - 1.0f, uu = cs - 0.9f;                            \
            float s0 = __expf(-500000.f * tt0 * tt0);                         \
            float e  = __expf(-50.f * uu * uu);                               \
            float rr = __expf(-20.f * cs);                                    \
            pkl[0][0] += s0; pkl[0][1] += e;                                  \
            _Pragma("unroll")                                                 \
            for (int kk = 0; kk < 9; ++kk) {                                  \
                e = e * rr * CkR[kk]; pkl[0][2 + kk] += e;                    \
            }                                                                 \
        }                                                                     \
        _Pragma("unroll")                                                     \
        for (int i = 0; i < 4; ++i) {                                         \
            float cs = ac1[i] * vq1 * iv4[i];                                 \
            cs = (cs > 0.f) ? cs : 2.0f;                                      \
            float tt0 = cs - 1.0f, uu = cs - 0.9f;                            \
            float s0 = __expf(-500000.f * tt0 * tt0);                         \
            float e  = __expf(-50.f * uu * uu);                               \
            float rr = __expf(-20.f * cs);                                    \
            pkl[1][0] += s0; pkl[1][1] += e;                                  \
            _Pragma("unroll")                                                 \
            for (int kk = 0; kk < 9; ++kk) {                                  \
                e = e * rr * CkR[kk]; pkl[1][2 + kk] += e;                    \
            }                                                                 \
        }                                                                     \
    }

    PITER(a00, a01, a02, a03, t0, "12")
    PITER(a10, a11, a12, a13, t1, "8")
    PITER(a20, a21, a22, a23, t2, "4")
    if (wv == 0) { PITER(a30, a31, a32, a33, t3, "0") }
    #undef PITER

    #pragma unroll
    for (int qt = 0; qt < 2; ++qt)
        #pragma unroll
        for (int k = 0; k < 11; ++k) {
            float v = pkl[qt][k];
            v += __shfl_xor(v, 16);
            v += __shfl_xor(v, 32);
            if (qd4 == 0) atomicAdd(&pk[(qt*16 + l15)*12 + k], v);
        }
    __syncthreads();

    if (tid < 11) {
        int k = tid;
        float s = 0.f;
        for (int q = 0; q < Qn; ++q)
            s += qmA[q] * 0.01f * __logf(fmaxf(pk[q*12 + k], 1e-10f));
        feats[(b*9 + qi*3 + dj)*11 + k] = s;
    }
}

// ---------------------------------------------------------------------------
__global__ void final_kernel(const float* __restrict__ feats,
                             const float* __restrict__ dw,
                             float* __restrict__ out) {
    int b = threadIdx.x;
    if (b < B_) {
        float s = 0.f;
        for (int f = 0; f < 99; ++f) s += feats[b*99 + f] * dw[f];
        out[b] = s;
    }
}

extern "C" void kernel_launch(void* const* d_in, const int* in_sizes, int n_in,
                              void* d_out, int out_size, void* d_ws, size_t ws_size,
                              hipStream_t stream) {
    const int*   qtok = (const int*)d_in[0];
    const int*   dtok = (const int*)d_in[1];
    const float* emb  = (const float*)d_in[2];
    const float* w1   = (const float*)d_in[3];
    const float* w2   = (const float*)d_in[4];
    const float* w3   = (const float*)d_in[5];
    const float* b1   = (const float*)d_in[6];
    const float* b2   = (const float*)d_in[7];
    const float* b3   = (const float*)d_in[8];
    const float* dw   = (const float*)d_in[9];
    float* out = (float*)d_out;

    char* w = (char*)d_ws;
    u16*   Wt3   = (u16*)w;                      // 491,520 B
    u16*   qg    = (u16*)(w + 491520);           // 3*128*32*128*2  = 3,145,728
    u16*   dgm   = (u16*)(w + 3637248);          // 3*128*208*128*2 = 20,447,232
    float* invq_ = (float*)(w + 24084480);       // 49,152
    float* invd_ = (float*)(w + 24133632);       // 319,488
    float* feats = (float*)(w + 24453120);       // 50,688 -> total 24,503,808

    prep_kernel<<<dim3(8, B_), 256, 0, stream>>>(w1, w2, w3, Wt3);

    conv_kernel<<<dim3(512), 512, 0, stream>>>(
        qtok, dtok, emb, Wt3, b1, b2, b3, qg, dgm, invq_, invd_);

    pool_kernel<<<dim3(3, B_, 3), 256, 0, stream>>>(qg, dgm, invq_, invd_, qtok, dtok, feats);

    final_kernel<<<1, 128, 0, stream>>>(feats, dw, out);
}

// Round 13
// 157.045 us; speedup vs baseline: 1.0872x; 1.0156x over previous
//
#include <hip/hip_runtime.h>
#include <hip/hip_bf16.h>
#include <math.h>

#define B_   128
#define Qn   30
#define Dn   200
#define En   300

typedef __attribute__((ext_vector_type(8))) short short8;
typedef __attribute__((ext_vector_type(4))) float floatx4;
typedef unsigned int u32;
typedef unsigned short u16;

static __device__ __forceinline__ u16 f2b(float x) {   // fp32 -> bf16 RNE
    union { float f; u32 u; } v; v.f = x;
    u32 r = v.u + 0x7FFFu + ((v.u >> 16) & 1u);
    return (u16)(r >> 16);
}
static __device__ __forceinline__ float bits2f(u32 u) {
    union { u32 u2; float f; } v; v.u2 = u; return v.f;
}

// asm load: issues at the program point; the compiler cannot sink it.
// Completion is OUR job: counted s_waitcnt vmcnt(N) + sched_barrier(0).
static __device__ __forceinline__ short8 gload16(const u16* p) {
    short8 r;
    asm volatile("global_load_dwordx4 %0, %1, off" : "=&v"(r) : "v"(p));
    return r;
}

#define MFMA __builtin_amdgcn_mfma_f32_16x16x32_bf16

// ---------------------------------------------------------------------------
// prep: weight permute + zero out[] (block (0,0); stream order makes it
// visible to pool's atomicAdds — required since the harness re-poisons
// d_out every iteration). ks-major Wt3: one K-slice = contiguous 48 KB.
// ---------------------------------------------------------------------------
__global__ void prep_kernel(
    const float* __restrict__ w1, const float* __restrict__ w2, const float* __restrict__ w3,
    u16* __restrict__ Wt3, float* __restrict__ out)
{
    if (blockIdx.x == 0 && blockIdx.y == 0 && threadIdx.x < B_)
        out[threadIdx.x] = 0.f;
    int p = (blockIdx.x*128 + blockIdx.y)*256 + threadIdx.x;
    if (p >= 245760) return;
    int ks = p / 24576;
    int r  = p - ks*24576;
    int g, rr;
    if (r < 4096)        { g = 0; rr = r;         }
    else if (r < 12288)  { g = 1; rr = r - 4096;  }
    else                 { g = 2; rr = r - 12288; }
    int j  = rr >> 12;
    int r2 = rr & 4095;
    int nt  = r2 >> 9;
    int q4  = (r2 >> 7) & 3;
    int c16 = (r2 >> 3) & 15;
    int k8  = r2 & 7;
    int ch = nt*16 + c16;
    int e  = ks*32 + q4*8 + k8;
    float v = 0.f;
    if (e < En) {
        if (g == 0)      v = w1[ch*En + e];
        else if (g == 1) v = w2[(ch*En + e)*2 + j];
        else             v = w3[(ch*En + e)*3 + j];
    }
    Wt3[p] = f2b(v);
}

// ---------------------------------------------------------------------------
// Fused conv (R12, FROZEN): wave wv owns a 16-ch strip (nt=wv) over all 64
// rows — zero intra-block B duplication, each B fragment feeds 4 MFMAs.
// B register-direct from L2-resident Wt3 with the compiler's schedule
// (R10's asm pipeline regressed here). Split A-gather, issue-early K-hi.
// ---------------------------------------------------------------------------
__global__ __launch_bounds__(512, 4) void conv_kernel(
    const int* __restrict__ qtok, const int* __restrict__ dtok,
    const float* __restrict__ emb,
    const u16* __restrict__ Wt3,
    const float* __restrict__ b1, const float* __restrict__ b2, const float* __restrict__ b3,
    u16* __restrict__ qg, u16* __restrict__ dg,
    float* __restrict__ invnq, float* __restrict__ invnd)
{
    __shared__ __align__(16) char smem[43560];   // As [66][656] + toks[66]
    char* As  = smem;
    int*  toks = (int*)(smem + 43296);

    const int tile = blockIdx.x;
    const int tid = threadIdx.x;
    const int wv = tid >> 6, lane = tid & 63;    // wv = 16-ch strip (nt)
    const int l15 = lane & 15, qd4 = lane >> 4;
    const int gR0 = tile*64;

    if (tid < 66) {
        int gr = gR0 + tid;
        int t = -1;
        if (gr < 32768) {
            int b = gr >> 8, pos = gr & 255;
            if (pos < Dn) t = dtok[b*Dn + pos];
            else if (pos >= 208 && pos < 238) t = qtok[b*Qn + (pos - 208)];
        }
        toks[tid] = t;
    }
    __syncthreads();

    // stage A K-lo: 66 rows x col4 0..39 (K elems 0..159) — all ks 0..4 reads
    #pragma unroll
    for (int i = 0; i < 6; ++i) {
        int idx = tid + i*512;
        if (idx < 2640) {
            int r = idx / 40, c4 = idx - r*40;
            int t = toks[r];
            u16 o0=0,o1=0,o2=0,o3=0;
            if (t >= 0) {
                float4 v = *(const float4*)(emb + t*En + c4*4);
                o0=f2b(v.x); o1=f2b(v.y); o2=f2b(v.z); o3=f2b(v.w);
            }
            u16* pdst = (u16*)(As + r*656 + c4*8);
            pdst[0]=o0; pdst[1]=o1; pdst[2]=o2; pdst[3]=o3;
        }
    }

    float bias[3];
    {
        int ch = wv*16 + l15;
        bias[0] = b1[ch];
        bias[1] = b2[ch];
        bias[2] = b3[ch];
    }

    floatx4 acc[3][4];                      // [gram][mt 16-row tile]
    #pragma unroll
    for (int g = 0; g < 3; ++g)
        #pragma unroll
        for (int mt = 0; mt < 4; ++mt)
            acc[g][mt] = (floatx4){0.f,0.f,0.f,0.f};

    __syncthreads();                        // A K-lo ready

    // K-hi loads (cols 160..319) issued into registers; fly under ks 0..4.
    float4 hf[6];
    #pragma unroll
    for (int i = 0; i < 6; ++i) {
        int idx = tid + i*512;
        const float* p = emb;               // safe dummy
        if (idx < 2640) {
            int r = idx / 40, c = idx - r*40;
            int t = toks[r];
            if (t >= 0 && c < 35) p = emb + t*En + (40 + c)*4;
        }
        hf[i] = *(const float4*)p;
    }

    #pragma unroll 1
    for (int ks = 0; ks < 5; ++ks) {
        const u16* Wks = Wt3 + ks*24576;
        #pragma unroll
        for (int j = 0; j < 3; ++j) {
            short8 afj[4];
            #pragma unroll
            for (int mt = 0; mt < 4; ++mt)
                afj[mt] = *(const short8*)(As + (mt*16 + l15 + j)*656 + ks*64 + qd4*16);
            #pragma unroll
            for (int g = 0; g < 3; ++g) {
                if (g < j) continue;
                const int cbW = (g == 0) ? 0 : (g == 1) ? 4096 : 12288;
                short8 wf = *(const short8*)(Wks + cbW + (j*8 + wv)*512 + lane*8);
                #pragma unroll
                for (int mt = 0; mt < 4; ++mt)
                    acc[g][mt] = MFMA(afj[mt], wf, acc[g][mt], 0, 0, 0);
            }
        }
    }

    // write K-hi into As (region untouched by ks 0..4 reads), one barrier
    #pragma unroll
    for (int i = 0; i < 6; ++i) {
        int idx = tid + i*512;
        if (idx < 2640) {
            int r = idx / 40, c = idx - r*40;
            int t = toks[r];
            bool ok = (t >= 0) && (c < 35);
            u16 o0=0,o1=0,o2=0,o3=0;
            if (ok) { o0=f2b(hf[i].x); o1=f2b(hf[i].y); o2=f2b(hf[i].z); o3=f2b(hf[i].w); }
            u16* pdst = (u16*)(As + r*656 + (40 + c)*8);
            pdst[0]=o0; pdst[1]=o1; pdst[2]=o2; pdst[3]=o3;
        }
    }
    __syncthreads();                        // K-hi ready

    #pragma unroll 1
    for (int ks = 5; ks < 10; ++ks) {
        const u16* Wks = Wt3 + ks*24576;
        #pragma unroll
        for (int j = 0; j < 3; ++j) {
            short8 afj[4];
            #pragma unroll
            for (int mt = 0; mt < 4; ++mt)
                afj[mt] = *(const short8*)(As + (mt*16 + l15 + j)*656 + ks*64 + qd4*16);
            #pragma unroll
            for (int g = 0; g < 3; ++g) {
                if (g < j) continue;
                const int cbW = (g == 0) ? 0 : (g == 1) ? 4096 : 12288;
                short8 wf = *(const short8*)(Wks + cbW + (j*8 + wv)*512 + lane*8);
                #pragma unroll
                for (int mt = 0; mt < 4; ++mt)
                    acc[g][mt] = MFMA(afj[mt], wf, acc[g][mt], 0, 0, 0);
            }
        }
    }

    // epilogue: per-gram Gs overlay on As; fully unrolled over g (rule #20);
    // norms across all 512 threads (8 lanes/row + shfl_xor).
    u16* Gs = (u16*)smem;                   // [64][136]
    #pragma unroll
    for (int g = 0; g < 3; ++g) {
        __syncthreads();
        {
            int ch = wv*16 + l15;
            #pragma unroll
            for (int mt = 0; mt < 4; ++mt)
                #pragma unroll
                for (int i = 0; i < 4; ++i) {
                    int row = mt*16 + qd4*4 + i;
                    Gs[row*136 + ch] = f2b(fmaxf(acc[g][mt][i] + bias[g], 0.f));
                }
        }
        __syncthreads();

        {
            int r = tid >> 3, pp = tid & 7;
            const char* rp = (const char*)Gs + r*272 + pp*32;
            float ssum = 0.f;
            #pragma unroll
            for (int t2 = 0; t2 < 2; ++t2) {
                uint4 u = *(const uint4*)(rp + t2*16);
                float x;
                x = bits2f(u.x << 16); ssum += x*x;  x = bits2f(u.x & 0xffff0000u); ssum += x*x;
                x = bits2f(u.y << 16); ssum += x*x;  x = bits2f(u.y & 0xffff0000u); ssum += x*x;
                x = bits2f(u.z << 16); ssum += x*x;  x = bits2f(u.z & 0xffff0000u); ssum += x*x;
                x = bits2f(u.w << 16); ssum += x*x;  x = bits2f(u.w & 0xffff0000u); ssum += x*x;
            }
            ssum += __shfl_xor(ssum, 1);
            ssum += __shfl_xor(ssum, 2);
            ssum += __shfl_xor(ssum, 4);
            if (pp == 0) {
                float inv = 1.f / (sqrtf(ssum) + 1e-13f);
                int gr = gR0 + r;
                int b = gr >> 8, pos = gr & 255;
                if (pos < 208)      invnd[(g*B_ + b)*208 + pos] = inv;
                else if (pos < 238) invnq[(g*B_ + b)*32 + (pos - 208)] = inv;
            }
        }
        #pragma unroll
        for (int i = 0; i < 2; ++i) {
            int idx = tid + i*512;
            int r = idx >> 4, c16 = idx & 15;
            uint4 v = *(const uint4*)((const char*)Gs + r*272 + c16*16);
            int gr = gR0 + r;
            int b = gr >> 8, pos = gr & 255;
            if (pos < 208)      *(uint4*)(dg + ((g*B_ + b)*208 + pos)*128 + c16*8) = v;
            else if (pos < 238) *(uint4*)(qg + ((g*B_ + b)*32 + (pos - 208))*128 + c16*8) = v;
        }
    }
}

// ---------------------------------------------------------------------------
// Pool, R13: R11 body (qi-split grid, L2-direct dg, asm issue-all-upfront
// loads + counted vmcnt — banked) with the FINAL DENSE LAYER FUSED: each
// block applies its 11-feature slice of dw and atomicAdds ONE scalar into
// out[b] (9 contributions per output; prep zeroes out). Saves the final
// kernel launch + gap. Only the 99-term fp32 dot order changes (~1e-6,
// vs 9.8e-4 bf16-dominated absmax).
// ---------------------------------------------------------------------------
__global__ __launch_bounds__(256, 2) void pool_kernel(
    const u16* __restrict__ qg, const u16* __restrict__ dg,
    const float* __restrict__ invnq, const float* __restrict__ invnd,
    const int* __restrict__ qtok, const int* __restrict__ dtok,
    const float* __restrict__ dw, float* __restrict__ out)
{
    __shared__ float pk[32*12];                    // 1536 B
    __shared__ float invqA[32];
    __shared__ float qmA[32];
    __shared__ float fl[11];
    __shared__ __align__(16) float invd[208];

    const int tid = threadIdx.x;
    const int b = blockIdx.y, dj = blockIdx.x, qi = blockIdx.z;
    const int wv = tid >> 6, lane = tid & 63;
    const int l15 = lane & 15, qd4 = lane >> 4;

    if (tid < 208) {
        float v = invnd[(dj*B_ + b)*208 + tid];
        bool ok = (tid < Dn) && (dtok[b*Dn + tid] > 0);
        invd[tid] = ok ? v : (-fabsf(v) - 1.0f);   // strictly negative if masked
    }
    if (tid < 32) {
        float v = invnq[(qi*B_ + b)*32 + tid];
        bool ok = (tid < Qn) && (qtok[b*Qn + tid] > 0);
        invqA[tid] = ok ? v : 0.f;
        qmA[tid] = ok ? 1.f : 0.f;
    }
    for (int i = tid; i < 32*12; i += 256) pk[i] = 0.f;
    __syncthreads();                        // drains prologue vmem: vmcnt==0 here

    // chain constants C_k = exp(10*(mu_k + mu_{k+1})), mu: 0.9,0.7,...,-0.9
    const float CkR[9] = {8886110.5f, 162754.79f, 2980.958f, 54.598150f, 1.0f,
                          0.018315639f, 3.3546263e-4f, 6.1442124e-6f, 1.1253517e-7f};

    const u16* qbase = qg + (size_t)((qi*B_ + b)*32)*128 + l15*128 + qd4*8;
    const u16* dbase = dg + (size_t)(dj*B_ + b)*208*128 + l15*128 + qd4*8;
    const int t0 = wv, t1 = wv + 4, t2 = wv + 8;
    const int t3 = (wv == 0) ? 12 : 11;     // clamped for wv>=1 (discarded)

    // ---- issue order defines vmcnt counts: qf(8), af0(4), af1(4), af2(4), af3(4)
    short8 q00 = gload16(qbase + 0*32);
    short8 q01 = gload16(qbase + 1*32);
    short8 q02 = gload16(qbase + 2*32);
    short8 q03 = gload16(qbase + 3*32);
    short8 q10 = gload16(qbase + 16*128 + 0*32);
    short8 q11 = gload16(qbase + 16*128 + 1*32);
    short8 q12 = gload16(qbase + 16*128 + 2*32);
    short8 q13 = gload16(qbase + 16*128 + 3*32);
    short8 a00 = gload16(dbase + t0*2048 + 0*32);
    short8 a01 = gload16(dbase + t0*2048 + 1*32);
    short8 a02 = gload16(dbase + t0*2048 + 2*32);
    short8 a03 = gload16(dbase + t0*2048 + 3*32);
    short8 a10 = gload16(dbase + t1*2048 + 0*32);
    short8 a11 = gload16(dbase + t1*2048 + 1*32);
    short8 a12 = gload16(dbase + t1*2048 + 2*32);
    short8 a13 = gload16(dbase + t1*2048 + 3*32);
    short8 a20 = gload16(dbase + t2*2048 + 0*32);
    short8 a21 = gload16(dbase + t2*2048 + 1*32);
    short8 a22 = gload16(dbase + t2*2048 + 2*32);
    short8 a23 = gload16(dbase + t2*2048 + 3*32);
    short8 a30 = gload16(dbase + t3*2048 + 0*32);
    short8 a31 = gload16(dbase + t3*2048 + 1*32);
    short8 a32 = gload16(dbase + t3*2048 + 2*32);
    short8 a33 = gload16(dbase + t3*2048 + 3*32);

    float vq0 = invqA[l15], vq1 = invqA[16 + l15];

    float pkl[2][11];
    #pragma unroll
    for (int qt = 0; qt < 2; ++qt)
        #pragma unroll
        for (int k = 0; k < 11; ++k) pkl[qt][k] = 0.f;

    // per-tile body; VMSTR counts the loads NOT yet needed (issue order above)
    #define PITER(A0, A1, A2, A3, TT, VMSTR)                                  \
    {                                                                         \
        asm volatile("s_waitcnt vmcnt(" VMSTR ")" ::: "memory");              \
        __builtin_amdgcn_sched_barrier(0);                                    \
        floatx4 ac0 = (floatx4){0.f,0.f,0.f,0.f};                             \
        floatx4 ac1 = (floatx4){0.f,0.f,0.f,0.f};                             \
        ac0 = MFMA(A0, q00, ac0, 0,0,0); ac1 = MFMA(A0, q10, ac1, 0,0,0);     \
        ac0 = MFMA(A1, q01, ac0, 0,0,0); ac1 = MFMA(A1, q11, ac1, 0,0,0);     \
        ac0 = MFMA(A2, q02, ac0, 0,0,0); ac1 = MFMA(A2, q12, ac1, 0,0,0);     \
        ac0 = MFMA(A3, q03, ac0, 0,0,0); ac1 = MFMA(A3, q13, ac1, 0,0,0);     \
        floatx4 iv4 = *(const floatx4*)(invd + (TT)*16 + qd4*4);              \
        _Pragma("unroll")                                                     \
        for (int i = 0; i < 4; ++i) {                                         \
            float cs = ac0[i] * vq0 * iv4[i];                                 \
            cs = (cs > 0.f) ? cs : 2.0f;                                      \
            float tt0 = cs - 1.0f, uu = cs - 0.9f;                            \
            float s0 = __expf(-500000.f * tt0 * tt0);                         \
            float e  = __expf(-50.f * uu * uu);                               \
            float rr = __expf(-20.f * cs);                                    \
            pkl[0][0] += s0; pkl[0][1] += e;                                  \
            _Pragma("unroll")                                                 \
            for (int kk = 0; kk < 9; ++kk) {                                  \
                e = e * rr * CkR[kk]; pkl[0][2 + kk] += e;                    \
            }                                                                 \
        }                                                                     \
        _Pragma("unroll")                                                     \
        for (int i = 0; i < 4; ++i) {                                         \
            float cs = ac1[i] * vq1 * iv4[i];                                 \
            cs = (cs > 0.f) ? cs : 2.0f;                                      \
            float tt0 = cs - 1.0f, uu = cs - 0.9f;                            \
            float s0 = __expf(-500000.f * tt0 * tt0);                         \
            float e  = __expf(-50.f * uu * uu);                               \
            float rr = __expf(-20.f * cs);                                    \
            pkl[1][0] += s0; pkl[1][1] += e;                                  \
            _Pragma("unroll")                                                 \
            for (int kk = 0; kk < 9; ++kk) {                                  \
                e = e * rr * CkR[kk]; pkl[1][2 + kk] += e;                    \
            }                                                                 \
        }                                                                     \
    }

    PITER(a00, a01, a02, a03, t0, "12")
    PITER(a10, a11, a12, a13, t1, "8")
    PITER(a20, a21, a22, a23, t2, "4")
    if (wv == 0) { PITER(a30, a31, a32, a33, t3, "0") }
    #undef PITER

    #pragma unroll
    for (int qt = 0; qt < 2; ++qt)
        #pragma unroll
        for (int k = 0; k < 11; ++k) {
            float v = pkl[qt][k];
            v += __shfl_xor(v, 16);
            v += __shfl_xor(v, 32);
            if (qd4 == 0) atomicAdd(&pk[(qt*16 + l15)*12 + k], v);
        }
    __syncthreads();

    if (tid < 11) {
        int k = tid;
        float s = 0.f;
        for (int q = 0; q < Qn; ++q)
            s += qmA[q] * 0.01f * __logf(fmaxf(pk[q*12 + k], 1e-10f));
        fl[k] = s * dw[(qi*3 + dj)*11 + k];    // fused dense-layer slice
    }
    __syncthreads();

    if (tid == 0) {
        float t = 0.f;
        #pragma unroll
        for (int k = 0; k < 11; ++k) t += fl[k];
        atomicAdd(&out[b], t);
    }
}

extern "C" void kernel_launch(void* const* d_in, const int* in_sizes, int n_in,
                              void* d_out, int out_size, void* d_ws, size_t ws_size,
                              hipStream_t stream) {
    const int*   qtok = (const int*)d_in[0];
    const int*   dtok = (const int*)d_in[1];
    const float* emb  = (const float*)d_in[2];
    const float* w1   = (const float*)d_in[3];
    const float* w2   = (const float*)d_in[4];
    const float* w3   = (const float*)d_in[5];
    const float* b1   = (const float*)d_in[6];
    const float* b2   = (const float*)d_in[7];
    const float* b3   = (const float*)d_in[8];
    const float* dw   = (const float*)d_in[9];
    float* out = (float*)d_out;

    char* w = (char*)d_ws;
    u16*   Wt3   = (u16*)w;                      // 491,520 B
    u16*   qg    = (u16*)(w + 491520);           // 3*128*32*128*2  = 3,145,728
    u16*   dgm   = (u16*)(w + 3637248);          // 3*128*208*128*2 = 20,447,232
    float* invq_ = (float*)(w + 24084480);       // 49,152
    float* invd_ = (float*)(w + 24133632);       // 319,488 -> total 24,453,120

    prep_kernel<<<dim3(8, B_), 256, 0, stream>>>(w1, w2, w3, Wt3, out);

    conv_kernel<<<dim3(512), 512, 0, stream>>>(
        qtok, dtok, emb, Wt3, b1, b2, b3, qg, dgm, invq_, invd_);

    pool_kernel<<<dim3(3, B_, 3), 256, 0, stream>>>(
        qg, dgm, invq_, invd_, qtok, dtok, dw, out);
}